// Round 7
// baseline (252.571 us; speedup 1.0000x reference)
//
#include <hip/hip_runtime.h>

#define NB 32
#define NC 256
#define NH 64
#define NW 64
#define NK 16
#define HW (NH * NW)          // 4096
#define NIT 4                 // consecutive h-rows per block
#define NBLK (NB * NH / NIT)  // 512 blocks = 2 per CU

typedef float f32x4 __attribute__((ext_vector_type(4)));

__device__ __forceinline__ float fsig(float z) {
    // sigmoid(z) = 1/(1+exp(-z)); fast exp + hw rcp (vs 5.9e-2 threshold: plenty)
    return __builtin_amdgcn_rcpf(1.0f + __expf(-z));
}

// 1024 threads; thread (cg=t>>4 in 0..63, q=t&15) owns channels 4cg..4cg+3 x w-quad q.
// Depth-2 register pipeline over 4 consecutive rows; __launch_bounds__(1024,8)
// forces <=64 VGPR so TWO blocks are resident per CU (32 waves) — pipeline (ILP)
// and TLP together. Peak live regs: xv[2][4]=32 + acc=16 + ~14 misc ≈ 62.
__global__ __launch_bounds__(1024, 8) void pse_kernel(
    const float* __restrict__ x,
    const float* __restrict__ w1,
    const float* __restrict__ b1,
    const float* __restrict__ w2,
    const float* __restrict__ b2,
    float* __restrict__ out)
{
    __shared__ float w2t[NK][NC + 4];  // w2 transposed -> w2t[k][c]
    __shared__ f32x4 part[16][17];     // per-wave folded partial sums [wave][q]
    __shared__ f32x4 hv4[NK][16];      // hidden layer hv[k][q]
    __shared__ float b2s[NC];

    const int t   = threadIdx.x;
    const int cg  = t >> 4;   // 0..63 : 4-channel group
    const int q   = t & 15;   // 0..15 : w-quad
    const int wid = t >> 6;   // 0..15 : wave id

    // block owns rows bh = blk*4 .. blk*4+3 (same b: NIT divides 64)
    const int bh0 = blockIdx.x * NIT;
    const int b   = bh0 >> 6;
    const int h0  = bh0 & 63;

    // single base per thread; row it, vec i live at +it*NW + i*HW (32-bit offsets)
    const size_t base = (size_t)b * NC * HW + (size_t)h0 * NW
                      + (size_t)(cg << 2) * HW + (q << 2);
    const float* __restrict__ xb = x + base;
    float* __restrict__ ob       = out + base;

    f32x4 xv[2][4];   // ping-pong register buffers (loop fully unrolled)

#define LOADROW(BUF, IT) { \
    _Pragma("unroll") \
    for (int _i = 0; _i < 4; ++_i) \
        BUF[_i] = __builtin_nontemporal_load( \
            reinterpret_cast<const f32x4*>(xb + (IT) * NW + _i * HW)); }

    // prologue: row 0 loads in flight while we stage w2/b2
    LOADROW(xv[0], 0)

    {
        const f32x4 v = reinterpret_cast<const f32x4*>(w2)[t];  // 1024 float4
        const int c  = t >> 2;
        const int k0 = (t & 3) << 2;
        w2t[k0 + 0][c] = v.x; w2t[k0 + 1][c] = v.y;
        w2t[k0 + 2][c] = v.z; w2t[k0 + 3][c] = v.w;
        if (t < NC) b2s[t] = b2[t];
    }
    float w1k = 0.f, b1k = 0.f;
    if (t < 256) { const int k = t >> 4; w1k = w1[k]; b1k = b1[k]; }

    #pragma unroll
    for (int it = 0; it < NIT; ++it) {
        const int cur = it & 1, nxt = cur ^ 1;

        // issue next row's loads first — they fly through the reduce/MLP/store below
        if (it + 1 < NIT) LOADROW(xv[nxt], it + 1)

        // ---- partial channel sum + in-wave fold (4 cg groups per wave)
        {
            f32x4 p = xv[cur][0] + xv[cur][1] + xv[cur][2] + xv[cur][3];
            p.x += __shfl_xor(p.x, 16, 64); p.y += __shfl_xor(p.y, 16, 64);
            p.z += __shfl_xor(p.z, 16, 64); p.w += __shfl_xor(p.w, 16, 64);
            p.x += __shfl_xor(p.x, 32, 64); p.y += __shfl_xor(p.y, 32, 64);
            p.z += __shfl_xor(p.z, 32, 64); p.w += __shfl_xor(p.w, 32, 64);
            if ((t & 63) < 16) part[wid][q] = p;
        }
        __syncthreads();

        // ---- final mean + hidden layer: thread (k=t>>4, q) for t<256
        if (t < 256) {
            f32x4 s = (f32x4)(0.f);
            #pragma unroll
            for (int i = 0; i < 16; ++i) s += part[i][q];   // broadcast reads
            s *= (1.0f / (float)NC);
            f32x4 hv;
            hv.x = fmaxf(fmaf(s.x, w1k, b1k), 0.f);
            hv.y = fmaxf(fmaf(s.y, w1k, b1k), 0.f);
            hv.z = fmaxf(fmaf(s.z, w1k, b1k), 0.f);
            hv.w = fmaxf(fmaf(s.w, w1k, b1k), 0.f);
            hv4[t >> 4][q] = hv;
        }
        __syncthreads();

        // ---- logits for 4 channels x quad, gate, store
        {
            f32x4 acc0 = (f32x4)(b2s[(cg << 2) + 0]);
            f32x4 acc1 = (f32x4)(b2s[(cg << 2) + 1]);
            f32x4 acc2 = (f32x4)(b2s[(cg << 2) + 2]);
            f32x4 acc3 = (f32x4)(b2s[(cg << 2) + 3]);
            #pragma unroll
            for (int k = 0; k < NK; ++k) {
                const f32x4 hk  = hv4[k][q];
                const f32x4 wvv = *reinterpret_cast<const f32x4*>(&w2t[k][cg << 2]);
                acc0 += hk * wvv.x; acc1 += hk * wvv.y;
                acc2 += hk * wvv.z; acc3 += hk * wvv.w;
            }
            float* _o = ob + it * NW;
            f32x4 r;
            r.x = xv[cur][0].x * fsig(acc0.x); r.y = xv[cur][0].y * fsig(acc0.y);
            r.z = xv[cur][0].z * fsig(acc0.z); r.w = xv[cur][0].w * fsig(acc0.w);
            __builtin_nontemporal_store(r, reinterpret_cast<f32x4*>(_o + 0 * HW));
            r.x = xv[cur][1].x * fsig(acc1.x); r.y = xv[cur][1].y * fsig(acc1.y);
            r.z = xv[cur][1].z * fsig(acc1.z); r.w = xv[cur][1].w * fsig(acc1.w);
            __builtin_nontemporal_store(r, reinterpret_cast<f32x4*>(_o + 1 * HW));
            r.x = xv[cur][2].x * fsig(acc2.x); r.y = xv[cur][2].y * fsig(acc2.y);
            r.z = xv[cur][2].z * fsig(acc2.z); r.w = xv[cur][2].w * fsig(acc2.w);
            __builtin_nontemporal_store(r, reinterpret_cast<f32x4*>(_o + 2 * HW));
            r.x = xv[cur][3].x * fsig(acc3.x); r.y = xv[cur][3].y * fsig(acc3.y);
            r.z = xv[cur][3].z * fsig(acc3.z); r.w = xv[cur][3].w * fsig(acc3.w);
            __builtin_nontemporal_store(r, reinterpret_cast<f32x4*>(_o + 3 * HW));
        }
    }
#undef LOADROW
}

extern "C" void kernel_launch(void* const* d_in, const int* in_sizes, int n_in,
                              void* d_out, int out_size, void* d_ws, size_t ws_size,
                              hipStream_t stream) {
    const float* x  = (const float*)d_in[0];
    const float* w1 = (const float*)d_in[1];
    const float* b1 = (const float*)d_in[2];
    const float* w2 = (const float*)d_in[3];
    const float* b2 = (const float*)d_in[4];
    float* out = (float*)d_out;

    hipLaunchKernelGGL(pse_kernel, dim3(NBLK), dim3(1024), 0, stream,
                       x, w1, b1, w2, b2, out);
}